// Round 1
// baseline (124.477 us; speedup 1.0000x reference)
//
#include <hip/hip_runtime.h>
#include <math.h>

// Problem constants (match reference)
#define NXC 1024
#define NYC 1024
#define DC  128
#define NCM1 4

// LDS tile row stride (floats): 136 = 128 + 8 pad.
// x reads: bank offsets 4*ty -> conflict-free. y reads: 2-way (free, m136).
#define LDS_STRIDE 136

// ws layout (float offsets)
#define WS_S      0            // 1024*1024
#define WS_ROWM   1048576      // 1024
#define WS_ROWL   1049600      // 1024
#define WS_COLM   1050624      // 1024
#define WS_COLL   1051648      // 1024
#define WS_PM     1052672      // 64*1024
#define WS_PL     1118208      // 64*1024
#define WS_ACC    1183744      // 2

// -------------------------------------------------------------------------
// Kernel 1: s[i,j] = -sum_d |zx[i,d] - zy[j,d]|
// 32x32 tile per block, 256 threads, 2x2 micro-tile per thread.
// -------------------------------------------------------------------------
__global__ __launch_bounds__(256) void compute_s_kernel(
    const float* __restrict__ zx, const float* __restrict__ zy,
    float* __restrict__ s)
{
    __shared__ float xs[32 * LDS_STRIDE];
    __shared__ float ys[32 * LDS_STRIDE];

    const int t  = threadIdx.x;
    const int x0 = blockIdx.y * 32;   // row tile base (z_x rows)
    const int y0 = blockIdx.x * 32;   // col tile base (z_y rows)

    // Stage 32x128 of each input. 1024 float4 per tile -> 4 per thread.
    #pragma unroll
    for (int k = 0; k < 4; ++k) {
        int idx = t + k * 256;      // float4 index in 32x(128/4)
        int r   = idx >> 5;         // row 0..31
        int c4  = idx & 31;         // float4 col 0..31
        float4 xv = ((const float4*)(zx + (size_t)(x0 + r) * DC))[c4];
        float4 yv = ((const float4*)(zy + (size_t)(y0 + r) * DC))[c4];
        *((float4*)(xs + r * LDS_STRIDE + c4 * 4)) = xv;
        *((float4*)(ys + r * LDS_STRIDE + c4 * 4)) = yv;
    }
    __syncthreads();

    const int tx = t & 15;          // col-pair index
    const int ty = t >> 4;          // row-pair index
    const int r0 = ty * 2;
    const int c0 = tx * 2;

    float a00 = 0.f, a01 = 0.f, a10 = 0.f, a11 = 0.f;

    #pragma unroll 4
    for (int d = 0; d < DC; d += 4) {
        float4 xa = *((const float4*)(xs + (r0    ) * LDS_STRIDE + d));
        float4 xb = *((const float4*)(xs + (r0 + 1) * LDS_STRIDE + d));
        float4 ya = *((const float4*)(ys + (c0    ) * LDS_STRIDE + d));
        float4 yb = *((const float4*)(ys + (c0 + 1) * LDS_STRIDE + d));

        a00 += fabsf(xa.x - ya.x) + fabsf(xa.y - ya.y) + fabsf(xa.z - ya.z) + fabsf(xa.w - ya.w);
        a01 += fabsf(xa.x - yb.x) + fabsf(xa.y - yb.y) + fabsf(xa.z - yb.z) + fabsf(xa.w - yb.w);
        a10 += fabsf(xb.x - ya.x) + fabsf(xb.y - ya.y) + fabsf(xb.z - ya.z) + fabsf(xb.w - ya.w);
        a11 += fabsf(xb.x - yb.x) + fabsf(xb.y - yb.y) + fabsf(xb.z - yb.z) + fabsf(xb.w - yb.w);
    }

    float* srow0 = s + (size_t)(x0 + r0) * NYC + y0 + c0;
    float* srow1 = s + (size_t)(x0 + r0 + 1) * NYC + y0 + c0;
    *((float2*)srow0) = make_float2(-a00, -a01);
    *((float2*)srow1) = make_float2(-a10, -a11);
}

// -------------------------------------------------------------------------
// Kernel 2: row softmax stats. One wave per row (4 rows/block, 256 blocks).
// -------------------------------------------------------------------------
__global__ __launch_bounds__(256) void row_stats_kernel(
    const float* __restrict__ s, float* __restrict__ row_m, float* __restrict__ row_l)
{
    const int wave = threadIdx.x >> 6;
    const int lane = threadIdx.x & 63;
    const int r = blockIdx.x * 4 + wave;
    const float4* row = (const float4*)(s + (size_t)r * NYC);

    float4 v[4];
    #pragma unroll
    for (int k = 0; k < 4; ++k) v[k] = row[lane + 64 * k];

    float m = -1e30f;
    #pragma unroll
    for (int k = 0; k < 4; ++k)
        m = fmaxf(m, fmaxf(fmaxf(v[k].x, v[k].y), fmaxf(v[k].z, v[k].w)));
    #pragma unroll
    for (int off = 32; off; off >>= 1) m = fmaxf(m, __shfl_xor(m, off, 64));

    float l = 0.f;
    #pragma unroll
    for (int k = 0; k < 4; ++k)
        l += __expf(v[k].x - m) + __expf(v[k].y - m) + __expf(v[k].z - m) + __expf(v[k].w - m);
    #pragma unroll
    for (int off = 32; off; off >>= 1) l += __shfl_xor(l, off, 64);

    if (lane == 0) { row_m[r] = m; row_l[r] = l; }
}

// -------------------------------------------------------------------------
// Kernel 3a: column softmax partials. grid (4 col-groups, 64 row-chunks of 16).
// Online softmax down each column chunk; coalesced reads.
// -------------------------------------------------------------------------
__global__ __launch_bounds__(256) void col_partial_kernel(
    const float* __restrict__ s, float* __restrict__ pm, float* __restrict__ pl)
{
    const int c  = blockIdx.x * 256 + threadIdx.x;
    const int rc = blockIdx.y;
    const int r0 = rc * 16;

    float m = -1e30f, l = 0.f;
    #pragma unroll 4
    for (int i = 0; i < 16; ++i) {
        float v  = s[(size_t)(r0 + i) * NYC + c];
        float nm = fmaxf(m, v);
        l = l * __expf(m - nm) + __expf(v - nm);
        m = nm;
    }
    pm[(size_t)rc * NYC + c] = m;
    pl[(size_t)rc * NYC + c] = l;
}

// -------------------------------------------------------------------------
// Kernel 3b: combine 64 column partials.
// -------------------------------------------------------------------------
__global__ __launch_bounds__(256) void col_combine_kernel(
    const float* __restrict__ pm, const float* __restrict__ pl,
    float* __restrict__ col_m, float* __restrict__ col_l)
{
    const int c = blockIdx.x * 256 + threadIdx.x;
    float m = -1e30f;
    #pragma unroll 8
    for (int k = 0; k < 64; ++k) m = fmaxf(m, pm[(size_t)k * NYC + c]);
    float l = 0.f;
    #pragma unroll 8
    for (int k = 0; k < 64; ++k) l += pl[(size_t)k * NYC + c] * __expf(pm[(size_t)k * NYC + c] - m);
    col_m[c] = m;
    col_l[c] = l;
}

// -------------------------------------------------------------------------
// Kernel 4: global reduction of S0 = sum(a+b-ab), S1 = sum((a+b-ab)*s).
// One block per row; one atomicAdd pair per block.
// -------------------------------------------------------------------------
__global__ __launch_bounds__(256) void reduce_kernel(
    const float* __restrict__ s,
    const float* __restrict__ row_m, const float* __restrict__ row_l,
    const float* __restrict__ col_m, const float* __restrict__ col_l,
    float* __restrict__ acc)
{
    const int r = blockIdx.x;
    const int t = threadIdx.x;

    const float rm    = row_m[r];
    const float rlinv = 1.f / row_l[r];

    float4 sv = ((const float4*)(s + (size_t)r * NYC))[t];
    float4 cm = ((const float4*)col_m)[t];
    float4 cl = ((const float4*)col_l)[t];

    float S0 = 0.f, S1 = 0.f;
    {
        float a = __expf(sv.x - rm) * rlinv;
        float b = __expf(sv.x - cm.x) / cl.x;
        float w = a + b - a * b;
        S0 += w; S1 += w * sv.x;
    }
    {
        float a = __expf(sv.y - rm) * rlinv;
        float b = __expf(sv.y - cm.y) / cl.y;
        float w = a + b - a * b;
        S0 += w; S1 += w * sv.y;
    }
    {
        float a = __expf(sv.z - rm) * rlinv;
        float b = __expf(sv.z - cm.z) / cl.z;
        float w = a + b - a * b;
        S0 += w; S1 += w * sv.z;
    }
    {
        float a = __expf(sv.w - rm) * rlinv;
        float b = __expf(sv.w - cm.w) / cl.w;
        float w = a + b - a * b;
        S0 += w; S1 += w * sv.w;
    }

    // wave reduce
    #pragma unroll
    for (int off = 32; off; off >>= 1) {
        S0 += __shfl_xor(S0, off, 64);
        S1 += __shfl_xor(S1, off, 64);
    }
    __shared__ float w0[4], w1[4];
    const int wave = t >> 6, lane = t & 63;
    if (lane == 0) { w0[wave] = S0; w1[wave] = S1; }
    __syncthreads();
    if (t == 0) {
        float t0 = w0[0] + w0[1] + w0[2] + w0[3];
        float t1 = w1[0] + w1[1] + w1[2] + w1[3];
        atomicAdd(&acc[0], t0);
        atomicAdd(&acc[1], t1);
    }
}

// -------------------------------------------------------------------------
// Kernel 5: logits = (S1/S0) * theta + beta
// -------------------------------------------------------------------------
__global__ void finalize_kernel(
    const float* __restrict__ acc,
    const float* __restrict__ theta, const float* __restrict__ beta,
    float* __restrict__ out)
{
    const int k = threadIdx.x;
    if (k < NCM1) {
        float c = acc[1] / acc[0];
        out[k] = c * theta[k] + beta[k];
    }
}

// -------------------------------------------------------------------------
extern "C" void kernel_launch(void* const* d_in, const int* in_sizes, int n_in,
                              void* d_out, int out_size, void* d_ws, size_t ws_size,
                              hipStream_t stream)
{
    const float* zx    = (const float*)d_in[0];
    const float* zy    = (const float*)d_in[1];
    const float* theta = (const float*)d_in[2];
    const float* beta  = (const float*)d_in[3];
    float* out = (float*)d_out;
    float* ws  = (float*)d_ws;

    float* s     = ws + WS_S;
    float* row_m = ws + WS_ROWM;
    float* row_l = ws + WS_ROWL;
    float* col_m = ws + WS_COLM;
    float* col_l = ws + WS_COLL;
    float* pm    = ws + WS_PM;
    float* pl    = ws + WS_PL;
    float* acc   = ws + WS_ACC;

    // zero the two accumulators (ws is poisoned 0xAA before every launch)
    hipMemsetAsync(acc, 0, 2 * sizeof(float), stream);

    dim3 gS(NYC / 32, NXC / 32);
    compute_s_kernel<<<gS, 256, 0, stream>>>(zx, zy, s);

    row_stats_kernel<<<NXC / 4, 256, 0, stream>>>(s, row_m, row_l);

    dim3 gC(NYC / 256, 64);
    col_partial_kernel<<<gC, 256, 0, stream>>>(s, pm, pl);
    col_combine_kernel<<<NYC / 256, 256, 0, stream>>>(pm, pl, col_m, col_l);

    reduce_kernel<<<NXC, 256, 0, stream>>>(s, row_m, row_l, col_m, col_l, acc);

    finalize_kernel<<<1, 64, 0, stream>>>(acc, theta, beta, out);
}

// Round 2
// 102.926 us; speedup vs baseline: 1.2094x; 1.2094x over previous
//
#include <hip/hip_runtime.h>
#include <math.h>

// Problem constants (match reference)
#define NXC 1024
#define NYC 1024
#define DC  128
#define NCM1 4

// ws layout (float offsets)
#define WS_S      0            // 1024*1024
#define WS_ROWM   1048576      // 1024
#define WS_ROWL   1049600      // 1024
#define WS_COLM   1050624      // 1024
#define WS_COLL   1051648      // 1024
#define WS_PM     1052672      // 64*1024
#define WS_PL     1118208      // 64*1024
#define WS_PART   1183744      // 256*2 (block partials S0,S1)

// -------------------------------------------------------------------------
// Kernel 1: s[i,j] = -sum_d |zx[i,d] - zy[j,d]|
// 64x64 tile per block (256 blocks), 256 threads as 16(tx) x 16(ty),
// 4x4 micro-tile per thread. LDS stores full 64x128 tiles of x and y with
// an XOR swizzle on the d index: element (r,d) lives at r*128 + (d ^ 4*((r>>2)&7)).
//   - x reads (rows 4ty..4ty+3): 4 distinct 16B groups, 16-lane broadcast -> conflict-free
//   - y reads (rows 4tx..4tx+3): 8 distinct groups covering 32 banks, 2-way -> free (m136)
//   - all reads 16B-aligned ds_read_b128
// -------------------------------------------------------------------------
__global__ __launch_bounds__(256) void compute_s_kernel(
    const float* __restrict__ zx, const float* __restrict__ zy,
    float* __restrict__ s)
{
    __shared__ __align__(16) float xs[64 * 128];
    __shared__ __align__(16) float ys[64 * 128];

    const int t  = threadIdx.x;
    const int y0 = blockIdx.x * 64;   // z_y rows (cols of s)
    const int x0 = blockIdx.y * 64;   // z_x rows (rows of s)

    // Stage 64x128 of each input: 2048 float4 per array, 8 per thread.
    #pragma unroll
    for (int k = 0; k < 8; ++k) {
        int idx = t + k * 256;        // float4 index
        int r   = idx >> 5;           // row 0..63
        int c4  = idx & 31;           // float4 col 0..31
        int dsw = (c4 * 4) ^ (4 * ((r >> 2) & 7));   // swizzled d
        float4 xv = ((const float4*)(zx + (size_t)(x0 + r) * DC))[c4];
        float4 yv = ((const float4*)(zy + (size_t)(y0 + r) * DC))[c4];
        *(float4*)(xs + r * 128 + dsw) = xv;
        *(float4*)(ys + r * 128 + dsw) = yv;
    }
    __syncthreads();

    const int tx = t & 15;
    const int ty = t >> 4;
    const int xsw = 4 * (ty & 7);     // swizzle const for rows 4ty..4ty+3
    const int ysw = 4 * (tx & 7);     // swizzle const for rows 4tx..4tx+3

    float acc[4][4];
    #pragma unroll
    for (int i = 0; i < 4; ++i)
        #pragma unroll
        for (int j = 0; j < 4; ++j) acc[i][j] = 0.f;

    const float* xb = xs + (4 * ty) * 128;
    const float* yb = ys + (4 * tx) * 128;

    #pragma unroll 4
    for (int d = 0; d < DC; d += 4) {
        float4 xv[4], yv[4];
        #pragma unroll
        for (int i = 0; i < 4; ++i) xv[i] = *(const float4*)(xb + i * 128 + (d ^ xsw));
        #pragma unroll
        for (int j = 0; j < 4; ++j) yv[j] = *(const float4*)(yb + j * 128 + (d ^ ysw));
        #pragma unroll
        for (int i = 0; i < 4; ++i)
            #pragma unroll
            for (int j = 0; j < 4; ++j) {
                acc[i][j] += fabsf(xv[i].x - yv[j].x) + fabsf(xv[i].y - yv[j].y)
                           + fabsf(xv[i].z - yv[j].z) + fabsf(xv[i].w - yv[j].w);
            }
    }

    #pragma unroll
    for (int i = 0; i < 4; ++i) {
        float4 o;
        o.x = -acc[i][0]; o.y = -acc[i][1]; o.z = -acc[i][2]; o.w = -acc[i][3];
        *(float4*)(s + (size_t)(x0 + 4 * ty + i) * NYC + y0 + 4 * tx) = o;
    }
}

// -------------------------------------------------------------------------
// Kernel 2: fused row stats + column partials over a 16-row band.
// 64 blocks x 256 threads. Thread t owns cols 4t..4t+3 for all 16 rows:
//   - column online softmax stats over the band -> pm/pl (no reduction needed)
//   - per-row (m,l) partials over its 4 cols -> block-reduced -> row_m/row_l
// Reads s exactly once.
// -------------------------------------------------------------------------
__global__ __launch_bounds__(256) void band_stats_kernel(
    const float* __restrict__ s,
    float* __restrict__ row_m, float* __restrict__ row_l,
    float* __restrict__ pm, float* __restrict__ pl)
{
    const int t  = threadIdx.x;
    const int rc = blockIdx.x;
    const int r0 = rc * 16;

    float4 cm = make_float4(-1e30f, -1e30f, -1e30f, -1e30f);
    float4 cl = make_float4(0.f, 0.f, 0.f, 0.f);
    float rm[16], rl[16];

    #pragma unroll
    for (int r = 0; r < 16; ++r) {
        float4 v = *(const float4*)(s + (size_t)(r0 + r) * NYC + 4 * t);

        // column online update (per component)
        float nm;
        nm = fmaxf(cm.x, v.x); cl.x = cl.x * __expf(cm.x - nm) + __expf(v.x - nm); cm.x = nm;
        nm = fmaxf(cm.y, v.y); cl.y = cl.y * __expf(cm.y - nm) + __expf(v.y - nm); cm.y = nm;
        nm = fmaxf(cm.z, v.z); cl.z = cl.z * __expf(cm.z - nm) + __expf(v.z - nm); cm.z = nm;
        nm = fmaxf(cm.w, v.w); cl.w = cl.w * __expf(cm.w - nm) + __expf(v.w - nm); cm.w = nm;

        // row partial over this thread's 4 cols
        float m = fmaxf(fmaxf(v.x, v.y), fmaxf(v.z, v.w));
        float l = __expf(v.x - m) + __expf(v.y - m) + __expf(v.z - m) + __expf(v.w - m);
        rm[r] = m; rl[r] = l;
    }

    // write column partials (coalesced float4)
    *(float4*)(pm + (size_t)rc * NYC + 4 * t) = cm;
    *(float4*)(pl + (size_t)rc * NYC + 4 * t) = cl;

    // block-reduce the 16 per-row (m,l) pairs
    #pragma unroll
    for (int r = 0; r < 16; ++r) {
        float m = rm[r], l = rl[r];
        #pragma unroll
        for (int off = 32; off; off >>= 1) {
            float mo = __shfl_xor(m, off, 64);
            float lo = __shfl_xor(l, off, 64);
            float nm = fmaxf(m, mo);
            l = l * __expf(m - nm) + lo * __expf(mo - nm);
            m = nm;
        }
        rm[r] = m; rl[r] = l;
    }
    __shared__ float sm[16][4], sl[16][4];
    const int wave = t >> 6, lane = t & 63;
    if (lane == 0) {
        #pragma unroll
        for (int r = 0; r < 16; ++r) { sm[r][wave] = rm[r]; sl[r][wave] = rl[r]; }
    }
    __syncthreads();
    if (t < 16) {
        float m = sm[t][0], l = sl[t][0];
        #pragma unroll
        for (int w = 1; w < 4; ++w) {
            float nm = fmaxf(m, sm[t][w]);
            l = l * __expf(m - nm) + sl[t][w] * __expf(sm[t][w] - nm);
            m = nm;
        }
        row_m[r0 + t] = m;
        row_l[r0 + t] = l;
    }
}

// -------------------------------------------------------------------------
// Kernel 3: combine 64 column partials -> col_m, col_l. 4 blocks x 256 thr,
// float4 per thread, online combine.
// -------------------------------------------------------------------------
__global__ __launch_bounds__(256) void col_combine_kernel(
    const float* __restrict__ pm, const float* __restrict__ pl,
    float* __restrict__ col_m, float* __restrict__ col_l)
{
    const int g = blockIdx.x * 256 + threadIdx.x;   // float4 col group

    float4 m = make_float4(-1e30f, -1e30f, -1e30f, -1e30f);
    float4 l = make_float4(0.f, 0.f, 0.f, 0.f);
    #pragma unroll 8
    for (int k = 0; k < 64; ++k) {
        float4 pmv = *(const float4*)(pm + (size_t)k * NYC + 4 * g);
        float4 plv = *(const float4*)(pl + (size_t)k * NYC + 4 * g);
        float nm;
        nm = fmaxf(m.x, pmv.x); l.x = l.x * __expf(m.x - nm) + plv.x * __expf(pmv.x - nm); m.x = nm;
        nm = fmaxf(m.y, pmv.y); l.y = l.y * __expf(m.y - nm) + plv.y * __expf(pmv.y - nm); m.y = nm;
        nm = fmaxf(m.z, pmv.z); l.z = l.z * __expf(m.z - nm) + plv.z * __expf(pmv.z - nm); m.z = nm;
        nm = fmaxf(m.w, pmv.w); l.w = l.w * __expf(m.w - nm) + plv.w * __expf(pmv.w - nm); m.w = nm;
    }
    *(float4*)(col_m + 4 * g) = m;
    *(float4*)(col_l + 4 * g) = l;
}

// -------------------------------------------------------------------------
// Kernel 4: S0 = sum(a+b-ab), S1 = sum((a+b-ab)*s). 256 blocks x 4 rows.
// Deterministic: block partials to ws (no atomics, no memset needed).
// -------------------------------------------------------------------------
__global__ __launch_bounds__(256) void reduce_kernel(
    const float* __restrict__ s,
    const float* __restrict__ row_m, const float* __restrict__ row_l,
    const float* __restrict__ col_m, const float* __restrict__ col_l,
    float* __restrict__ part)
{
    const int b = blockIdx.x;
    const int t = threadIdx.x;

    float4 cm = *(const float4*)(col_m + 4 * t);
    float4 cl = *(const float4*)(col_l + 4 * t);

    float S0 = 0.f, S1 = 0.f;
    #pragma unroll
    for (int r = 0; r < 4; ++r) {
        const int row = 4 * b + r;
        const float rmv   = row_m[row];
        const float rlinv = 1.f / row_l[row];
        float4 sv = *(const float4*)(s + (size_t)row * NYC + 4 * t);
        {
            float a = __expf(sv.x - rmv) * rlinv;
            float bb = __expf(sv.x - cm.x) / cl.x;
            float w = a + bb - a * bb;
            S0 += w; S1 += w * sv.x;
        }
        {
            float a = __expf(sv.y - rmv) * rlinv;
            float bb = __expf(sv.y - cm.y) / cl.y;
            float w = a + bb - a * bb;
            S0 += w; S1 += w * sv.y;
        }
        {
            float a = __expf(sv.z - rmv) * rlinv;
            float bb = __expf(sv.z - cm.z) / cl.z;
            float w = a + bb - a * bb;
            S0 += w; S1 += w * sv.z;
        }
        {
            float a = __expf(sv.w - rmv) * rlinv;
            float bb = __expf(sv.w - cm.w) / cl.w;
            float w = a + bb - a * bb;
            S0 += w; S1 += w * sv.w;
        }
    }

    #pragma unroll
    for (int off = 32; off; off >>= 1) {
        S0 += __shfl_xor(S0, off, 64);
        S1 += __shfl_xor(S1, off, 64);
    }
    __shared__ float w0[4], w1[4];
    const int wave = t >> 6, lane = t & 63;
    if (lane == 0) { w0[wave] = S0; w1[wave] = S1; }
    __syncthreads();
    if (t == 0) {
        part[2 * b]     = w0[0] + w0[1] + w0[2] + w0[3];
        part[2 * b + 1] = w1[0] + w1[1] + w1[2] + w1[3];
    }
}

// -------------------------------------------------------------------------
// Kernel 5: sum 256 partials, logits = (S1/S0)*theta + beta
// -------------------------------------------------------------------------
__global__ __launch_bounds__(256) void finalize_kernel(
    const float* __restrict__ part,
    const float* __restrict__ theta, const float* __restrict__ beta,
    float* __restrict__ out)
{
    const int t = threadIdx.x;
    float2 p = *(const float2*)(part + 2 * t);
    float S0 = p.x, S1 = p.y;
    #pragma unroll
    for (int off = 32; off; off >>= 1) {
        S0 += __shfl_xor(S0, off, 64);
        S1 += __shfl_xor(S1, off, 64);
    }
    __shared__ float w0[4], w1[4];
    const int wave = t >> 6, lane = t & 63;
    if (lane == 0) { w0[wave] = S0; w1[wave] = S1; }
    __syncthreads();
    if (t < NCM1) {
        float t0 = w0[0] + w0[1] + w0[2] + w0[3];
        float t1 = w1[0] + w1[1] + w1[2] + w1[3];
        float c = t1 / t0;
        out[t] = c * theta[t] + beta[t];
    }
}

// -------------------------------------------------------------------------
extern "C" void kernel_launch(void* const* d_in, const int* in_sizes, int n_in,
                              void* d_out, int out_size, void* d_ws, size_t ws_size,
                              hipStream_t stream)
{
    const float* zx    = (const float*)d_in[0];
    const float* zy    = (const float*)d_in[1];
    const float* theta = (const float*)d_in[2];
    const float* beta  = (const float*)d_in[3];
    float* out = (float*)d_out;
    float* ws  = (float*)d_ws;

    float* s     = ws + WS_S;
    float* row_m = ws + WS_ROWM;
    float* row_l = ws + WS_ROWL;
    float* col_m = ws + WS_COLM;
    float* col_l = ws + WS_COLL;
    float* pm    = ws + WS_PM;
    float* pl    = ws + WS_PL;
    float* part  = ws + WS_PART;

    dim3 gS(NYC / 64, NXC / 64);
    compute_s_kernel<<<gS, 256, 0, stream>>>(zx, zy, s);

    band_stats_kernel<<<64, 256, 0, stream>>>(s, row_m, row_l, pm, pl);

    col_combine_kernel<<<NYC / 256, 256, 0, stream>>>(pm, pl, col_m, col_l);

    reduce_kernel<<<NXC / 4, 256, 0, stream>>>(s, row_m, row_l, col_m, col_l, part);

    finalize_kernel<<<1, 256, 0, stream>>>(part, theta, beta, out);
}